// Round 1
// baseline (95.146 us; speedup 1.0000x reference)
//
#include <hip/hip_runtime.h>

// Problem constants
constexpr int W   = 240;
constexpr int H   = 128;
constexpr int D   = 48;   // disparity bins
constexpr int G   = 40;   // groups
constexpr int CPG = 8;    // channels per group (320/40)
constexpr int CC  = 12;   // concat channels
constexpr int HW  = H * W;
constexpr int PAD = 48;        // left zero-pad so tgt[w-d] (w<d) reads zeros
constexpr int TROW = PAD + W;  // 288 floats per padded row

constexpr int NGWC = G * H;       // 5120 gwc blocks
constexpr int NCAT = 2 * CC * H;  // 3072 concat blocks (c2 0..23 x h)
// Interleave 5 gwc : 3 cat per group of 8 consecutive blockIdx (5120/3072 = 5/3)
constexpr int NGRID = NGWC + NCAT;  // 8192

// True 16B vector type so nontemporal load/store emit single dwordx4 nt ops
// (4 scalar nt stores = 60 lanes x 4B at 16B stride per instruction -> 25%
// cacheline coverage; streaming policy may flush partial lines to HBM).
typedef float f4 __attribute__((ext_vector_type(4)));

__device__ __forceinline__ void nt_store(float* p, f4 v) {
  __builtin_nontemporal_store(v, (f4*)p);
}
__device__ __forceinline__ f4 nt_load(const float* p) {
  return __builtin_nontemporal_load((const f4*)p);
}

// ---------------------------------------------------------------------------
// Fused kernel.
// Type A (gwc): one block per (g, h). LDS ref[8][240] + tgt[8][288 padded].
//   lane = w4 (60 active), wave dq -> 12 consecutive d via one aligned
//   16-float register window per channel + static slices. mean/8 epilogue.
// Type B (cat): one block per (c2, h). LDS one padded row. Same lane/d
//   mapping; ref half = mask-select, tgt half = window slices. Pure copy.
// ---------------------------------------------------------------------------
__global__ __launch_bounds__(256) void fused_kernel(const float* __restrict__ ref,
                                                    const float* __restrict__ tgt,
                                                    const float* __restrict__ refc,
                                                    const float* __restrict__ tgtc,
                                                    float* __restrict__ out) {
  __shared__ float sref[CPG][W];
  __shared__ float stgt[CPG][TROW];

  const int bid = blockIdx.x;
  const int grp = bid >> 3;
  const int rr  = bid & 7;
  const int tid = threadIdx.x;

  const int lane = tid & 63;
  const int dq   = tid >> 6;   // 0..3 -> d block of 12
  const int w4   = lane;       // active if < 60
  const int d0   = dq * 12;

  if (rr < 5) {
    // ---------------- Type A: groupwise correlation ----------------
    const int aid = grp * 5 + rr;      // 0..5119
    const int g   = aid >> 7;
    const int h   = aid & (H - 1);

    for (int p = tid; p < CPG * (PAD / 4); p += 256) {
      int c = p / (PAD / 4);
      int i = p - c * (PAD / 4);
      *(f4*)&stgt[c][i * 4] = f4{0.f, 0.f, 0.f, 0.f};
    }
    const size_t rowbase = (size_t)(g * CPG) * HW + (size_t)h * W;
    for (int q = tid; q < CPG * (W / 4); q += 256) {
      int c  = q / (W / 4);
      int x4 = q - c * (W / 4);
      f4 rv = nt_load(&ref[rowbase + (size_t)c * HW + x4 * 4]);
      f4 tv = nt_load(&tgt[rowbase + (size_t)c * HW + x4 * 4]);
      *(f4*)&sref[c][x4 * 4]       = rv;
      *(f4*)&stgt[c][PAD + x4 * 4] = tv;
    }
    __syncthreads();
    if (w4 >= W / 4) return;

    f4 acc[12];
#pragma unroll
    for (int j = 0; j < 12; ++j) acc[j] = f4{0.f, 0.f, 0.f, 0.f};

    const int base = 4 * w4 - d0 - 12;   // aligned (d0 % 4 == 0)
#pragma unroll
    for (int c = 0; c < CPG; ++c) {
      f4 r = *(const f4*)&sref[c][4 * w4];
      const f4* tp = (const f4*)&stgt[c][PAD + base];
      float tt[16];
      *(f4*)&tt[0]  = tp[0];
      *(f4*)&tt[4]  = tp[1];
      *(f4*)&tt[8]  = tp[2];
      *(f4*)&tt[12] = tp[3];
#pragma unroll
      for (int j = 0; j < 12; ++j) {   // d = d0 + j; window = tt[12-j .. 15-j]
        acc[j].x += r.x * tt[12 - j];
        acc[j].y += r.y * tt[13 - j];
        acc[j].z += r.z * tt[14 - j];
        acc[j].w += r.w * tt[15 - j];
      }
    }

    float* op = out + ((size_t)(g * D + d0) * H + h) * W + 4 * w4;
#pragma unroll
    for (int j = 0; j < 12; ++j) {
      nt_store(op, acc[j] * 0.125f);
      op += HW;
    }
  } else {
    // ---------------- Type B: concat volume ----------------
    const int cid = grp * 3 + (rr - 5);  // 0..3071
    const int c2  = cid >> 7;            // 0..23
    const int h   = cid & (H - 1);
    float* srow = &stgt[0][0];           // TROW floats

    if (tid < PAD / 4)
      *(f4*)&srow[tid * 4] = f4{0.f, 0.f, 0.f, 0.f};
    const bool is_ref = (c2 < CC);
    const float* src = is_ref ? (refc + (size_t)c2 * HW + (size_t)h * W)
                              : (tgtc + (size_t)(c2 - CC) * HW + (size_t)h * W);
    if (tid < W / 4)
      *(f4*)&srow[PAD + tid * 4] = nt_load(&src[tid * 4]);
    __syncthreads();
    if (w4 >= W / 4) return;

    float* op = out + ((size_t)((G + c2) * D + d0) * H + h) * W + 4 * w4;
    if (is_ref) {
      const f4 rv = *(const f4*)&srow[PAD + 4 * w4];
      const int w0 = 4 * w4;
#pragma unroll
      for (int j = 0; j < 12; ++j) {
        const int d = d0 + j;
        f4 v;
        v.x = (w0 + 0 >= d) ? rv.x : 0.f;
        v.y = (w0 + 1 >= d) ? rv.y : 0.f;
        v.z = (w0 + 2 >= d) ? rv.z : 0.f;
        v.w = (w0 + 3 >= d) ? rv.w : 0.f;
        nt_store(op, v);
        op += HW;
      }
    } else {
      const int base = 4 * w4 - d0 - 12;
      const f4* tp = (const f4*)&srow[PAD + base];
      float tt[16];
      *(f4*)&tt[0]  = tp[0];
      *(f4*)&tt[4]  = tp[1];
      *(f4*)&tt[8]  = tp[2];
      *(f4*)&tt[12] = tp[3];
#pragma unroll
      for (int j = 0; j < 12; ++j) {
        f4 v = {tt[12 - j], tt[13 - j], tt[14 - j], tt[15 - j]};
        nt_store(op, v);
        op += HW;
      }
    }
  }
}

extern "C" void kernel_launch(void* const* d_in, const int* in_sizes, int n_in,
                              void* d_out, int out_size, void* d_ws, size_t ws_size,
                              hipStream_t stream) {
  const float* ref_gwc    = (const float*)d_in[0];
  const float* tgt_gwc    = (const float*)d_in[1];
  const float* ref_concat = (const float*)d_in[2];
  const float* tgt_concat = (const float*)d_in[3];
  float* out = (float*)d_out;

  fused_kernel<<<NGRID, 256, 0, stream>>>(ref_gwc, tgt_gwc, ref_concat,
                                          tgt_concat, out);
}

// Round 2
// 89.065 us; speedup vs baseline: 1.0683x; 1.0683x over previous
//
#include <hip/hip_runtime.h>

// Problem constants
constexpr int W   = 240;
constexpr int H   = 128;
constexpr int D   = 48;   // disparity bins
constexpr int G   = 40;   // groups
constexpr int CPG = 8;    // channels per group (320/40)
constexpr int CC  = 12;   // concat channels
constexpr int HW  = H * W;
constexpr int PAD = 48;        // left zero-pad so tgt[w-d] (w<d) reads zeros
constexpr int TROW = PAD + W;  // 288 floats per padded row

// h-pair blocks: each block covers two adjacent h rows (h0, h0+1) with
// 512 threads = 8 waves. Wave (dq, hh) handles d-range [dq*12, dq*12+12)
// for row h0+hh. The paired waves (dq,0)/(dq,1) run identical post-barrier
// code, so their 960B stores to adjacent h rows of the SAME d-plane land
// ~simultaneously -> 1920B-contiguous write bursts (DRAM row locality).
constexpr int HP   = H / 2;        // 64 h-pairs
constexpr int NGWC = G * HP;       // 2560 gwc blocks
constexpr int NCAT = 2 * CC * HP;  // 1536 concat blocks
// Interleave 5 gwc : 3 cat per group of 8 consecutive blockIdx (2560/1536 = 5/3)
constexpr int NGRID = NGWC + NCAT;  // 4096

__device__ __forceinline__ void nt_store4(float* p, float4 v) {
  __builtin_nontemporal_store(v.x, p + 0);
  __builtin_nontemporal_store(v.y, p + 1);
  __builtin_nontemporal_store(v.z, p + 2);
  __builtin_nontemporal_store(v.w, p + 3);
}

// ---------------------------------------------------------------------------
// Fused kernel.
// Type A (gwc): one block per (g, h-pair). LDS ref[8][2][240] + tgt[8][2][288].
//   lane = w4 (60 active), wave (dq,hh) -> 12 consecutive d of row h0+hh via
//   one aligned 16-float register window per channel + static slices.
// Type B (cat): one block per (c2, h-pair). LDS two padded rows. Same
//   wave/d mapping; ref half = mask-select, tgt half = window slices.
// Loads are PLAIN (cached) — inputs are L3-resident across iterations;
// nt loads measured +9.3us (round 1). Stores are nontemporal (output 377MB
// streams past L3 and is never re-read).
// ---------------------------------------------------------------------------
__global__ __launch_bounds__(512) void fused_kernel(const float* __restrict__ ref,
                                                    const float* __restrict__ tgt,
                                                    const float* __restrict__ refc,
                                                    const float* __restrict__ tgtc,
                                                    float* __restrict__ out) {
  __shared__ float sref[CPG][2][W];     // 15360 B
  __shared__ float stgt[CPG][2][TROW];  // 18432 B

  const int bid = blockIdx.x;
  const int grp = bid >> 3;
  const int rr  = bid & 7;
  const int tid = threadIdx.x;

  const int lane = tid & 63;
  const int wid  = tid >> 6;   // 0..7
  const int dq   = wid >> 1;   // 0..3 -> d block of 12
  const int hh   = wid & 1;    // row within pair
  const int w4   = lane;       // active if < 60
  const int d0   = dq * 12;

  if (rr < 5) {
    // ---------------- Type A: groupwise correlation ----------------
    const int aid = grp * 5 + rr;      // 0..2559
    const int g   = aid >> 6;          // 0..39
    const int hp  = aid & (HP - 1);    // 0..63
    const int h0  = hp * 2;

    // zero the left pads: 8c x 2h x 12 float4
    if (tid < 256) {
      int c  = tid >> 5;
      int r5 = tid & 31;
      int h2 = r5 >> 4;
      int i  = r5 & 15;
      if (i < PAD / 4)
        *(float4*)&stgt[c][h2][i * 4] = make_float4(0.f, 0.f, 0.f, 0.f);
    }
    // stage both rows of ref+tgt: 1024 slots (8c x 2h x 64), 60/64 active
    const size_t rowbase = (size_t)(g * CPG) * HW + (size_t)h0 * W;
    for (int p = tid; p < 1024; p += 512) {
      int c   = p >> 7;
      int rem = p & 127;
      int h2  = rem >> 6;
      int x4  = rem & 63;
      if (x4 < W / 4) {
        size_t src = rowbase + (size_t)c * HW + (size_t)h2 * W + x4 * 4;
        float4 rv = *(const float4*)&ref[src];
        float4 tv = *(const float4*)&tgt[src];
        *(float4*)&sref[c][h2][x4 * 4]       = rv;
        *(float4*)&stgt[c][h2][PAD + x4 * 4] = tv;
      }
    }
    __syncthreads();
    if (w4 >= W / 4) return;

    float4 acc[12];
#pragma unroll
    for (int j = 0; j < 12; ++j) acc[j] = make_float4(0.f, 0.f, 0.f, 0.f);

    const int base = 4 * w4 - d0 - 12;   // aligned (d0 % 4 == 0)
#pragma unroll
    for (int c = 0; c < CPG; ++c) {
      float4 r = *(const float4*)&sref[c][hh][4 * w4];
      const float4* tp = (const float4*)&stgt[c][hh][PAD + base];
      float tt[16];
      *(float4*)&tt[0]  = tp[0];
      *(float4*)&tt[4]  = tp[1];
      *(float4*)&tt[8]  = tp[2];
      *(float4*)&tt[12] = tp[3];
#pragma unroll
      for (int j = 0; j < 12; ++j) {   // d = d0 + j; window = tt[12-j .. 15-j]
        acc[j].x += r.x * tt[12 - j];
        acc[j].y += r.y * tt[13 - j];
        acc[j].z += r.z * tt[14 - j];
        acc[j].w += r.w * tt[15 - j];
      }
    }

    float* op = out + ((size_t)(g * D + d0) * H + (h0 + hh)) * W + 4 * w4;
#pragma unroll
    for (int j = 0; j < 12; ++j) {
      nt_store4(op, make_float4(acc[j].x * 0.125f, acc[j].y * 0.125f,
                                acc[j].z * 0.125f, acc[j].w * 0.125f));
      op += HW;
    }
  } else {
    // ---------------- Type B: concat volume ----------------
    const int cid = grp * 3 + (rr - 5);  // 0..1535
    const int c2  = cid >> 6;            // 0..23
    const int hp  = cid & (HP - 1);      // 0..63
    const int h0  = hp * 2;

    // two padded rows live in stgt[0][0..1][*]
    if (tid < 32) {
      int h2 = tid >> 4;
      int i  = tid & 15;
      if (i < PAD / 4)
        *(float4*)&stgt[0][h2][i * 4] = make_float4(0.f, 0.f, 0.f, 0.f);
    }
    const bool is_ref = (c2 < CC);
    const float* src = is_ref ? (refc + (size_t)c2 * HW + (size_t)h0 * W)
                              : (tgtc + (size_t)(c2 - CC) * HW + (size_t)h0 * W);
    if (tid < 128) {
      int h2 = tid >> 6;
      int x4 = tid & 63;
      if (x4 < W / 4)
        *(float4*)&stgt[0][h2][PAD + x4 * 4] = *(const float4*)&src[h2 * W + x4 * 4];
    }
    __syncthreads();
    if (w4 >= W / 4) return;

    const float* srow = &stgt[0][hh][0];
    float* op = out + ((size_t)((G + c2) * D + d0) * H + (h0 + hh)) * W + 4 * w4;
    if (is_ref) {
      const float4 rv = *(const float4*)&srow[PAD + 4 * w4];
      const int w0 = 4 * w4;
#pragma unroll
      for (int j = 0; j < 12; ++j) {
        const int d = d0 + j;
        float4 v;
        v.x = (w0 + 0 >= d) ? rv.x : 0.f;
        v.y = (w0 + 1 >= d) ? rv.y : 0.f;
        v.z = (w0 + 2 >= d) ? rv.z : 0.f;
        v.w = (w0 + 3 >= d) ? rv.w : 0.f;
        nt_store4(op, v);
        op += HW;
      }
    } else {
      const int base = 4 * w4 - d0 - 12;
      const float4* tp = (const float4*)&srow[PAD + base];
      float tt[16];
      *(float4*)&tt[0]  = tp[0];
      *(float4*)&tt[4]  = tp[1];
      *(float4*)&tt[8]  = tp[2];
      *(float4*)&tt[12] = tp[3];
#pragma unroll
      for (int j = 0; j < 12; ++j) {
        nt_store4(op, make_float4(tt[12 - j], tt[13 - j], tt[14 - j], tt[15 - j]));
        op += HW;
      }
    }
  }
}

extern "C" void kernel_launch(void* const* d_in, const int* in_sizes, int n_in,
                              void* d_out, int out_size, void* d_ws, size_t ws_size,
                              hipStream_t stream) {
  const float* ref_gwc    = (const float*)d_in[0];
  const float* tgt_gwc    = (const float*)d_in[1];
  const float* ref_concat = (const float*)d_in[2];
  const float* tgt_concat = (const float*)d_in[3];
  float* out = (float*)d_out;

  fused_kernel<<<NGRID, 512, 0, stream>>>(ref_gwc, tgt_gwc, ref_concat,
                                          tgt_concat, out);
}